// Round 1
// baseline (12382.437 us; speedup 1.0000x reference)
//
#include <hip/hip_runtime.h>
#include <hip/hip_bf16.h>

#define HID 128
#define SDIM 48
#define NSTEP 511
#define TFULL 512
#define ROWS 16
#define NGATE 512

__device__ __forceinline__ float sigm(float x)  { return 1.0f/(1.0f+__expf(-x)); }
__device__ __forceinline__ float tanh_f(float x){ return 2.0f/(1.0f+__expf(-2.0f*x)) - 1.0f; }

// ws layout: wih_t f32 [49][512] @0 (100352 B); whh_t bf16 [128][512] @100352 (131072 B);
//            bias  f32 [512]     @231424 (2048 B)
__global__ void setup_weights(const float* __restrict__ w_ih, const float* __restrict__ w_hh,
                              const float* __restrict__ b_ih, const float* __restrict__ b_hh,
                              float* __restrict__ wih_t, __hip_bfloat16* __restrict__ whh_t,
                              float* __restrict__ bias) {
  int stride = gridDim.x * blockDim.x;
  int i0 = blockIdx.x * blockDim.x + threadIdx.x;
  for (int idx = i0; idx < 49*NGATE; idx += stride) {
    int k = idx >> 9, g = idx & 511;
    wih_t[idx] = w_ih[g*49 + k];
  }
  for (int idx = i0; idx < HID*NGATE; idx += stride) {
    int k = idx >> 9, g = idx & 511;
    whh_t[idx] = __float2bfloat16(w_hh[g*HID + k]);
  }
  for (int idx = i0; idx < NGATE; idx += stride)
    bias[idx] = b_ih[idx] + b_hh[idx];
}

// One block per 16 batch rows, persistent over all 511 steps.
// Thread t: hidden unit u = t&127, row-half rhalf = t>>7 (rows r0..r0+7).
// Owns gates {u, 128+u, 256+u, 384+u} for its 8 rows; c kept in registers.
__global__ __launch_bounds__(256, 1)
void lstm_persistent(const float* __restrict__ y_flow,
                     const float* __restrict__ x_statics,
                     const int* __restrict__ twin_p,
                     const float* __restrict__ enc_w1, const float* __restrict__ enc_b1,
                     const float* __restrict__ enc_w2, const float* __restrict__ enc_b2,
                     const float* __restrict__ out_w, const float* __restrict__ out_b,
                     const float* __restrict__ wih_t, const __hip_bfloat16* __restrict__ whh_t,
                     const float* __restrict__ bias,
                     float* __restrict__ out) {
  __shared__ __hip_bfloat16 s_whh[HID*NGATE];   // 131072 B, [k][512]
  __shared__ float s_xh[177*17];                // x_in(49)+h(128) rows x 16 batch (pad 17)
  __shared__ float s_xs[ROWS*49];
  __shared__ float s_e1[ROWS*49];
  __shared__ __hip_bfloat16 s_w1[SDIM*49];
  __shared__ __hip_bfloat16 s_w2[SDIM*49];
  __shared__ float s_b1[SDIM];
  __shared__ float s_b2[SDIM];
  __shared__ float s_pp[4][8];
  // total ~159.3 KB < 160 KiB

  const int tid = threadIdx.x;
  const int blk = blockIdx.x;
  const int u = tid & 127;
  const int rhalf = tid >> 7;
  const int r0 = rhalf << 3;

  for (int idx = tid; idx < HID*NGATE; idx += 256) s_whh[idx] = whh_t[idx];
  for (int idx = tid; idx < SDIM*SDIM; idx += 256) {
    int j = idx / SDIM, k = idx - j*SDIM;
    s_w1[j*49 + k] = __float2bfloat16(enc_w1[idx]);
    s_w2[j*49 + k] = __float2bfloat16(enc_w2[idx]);
  }
  if (tid < SDIM) { s_b1[tid] = enc_b1[tid]; s_b2[tid] = enc_b2[tid]; }
  for (int idx = tid; idx < HID*ROWS; idx += 256) {        // zero h slots
    int k = 49 + (idx >> 4), rr = idx & 15;
    s_xh[k*17 + rr] = 0.0f;
  }
  if (tid < ROWS) {                                        // flow(t=0) = teacher[0]
    size_t b = (size_t)blk*ROWS + tid;
    s_xh[tid] = y_flow[b*TFULL];
  }
  const int twc = twin_p[0] - 1;     // teacher iff step < twin_idx-1
  const float ow = out_w[u];
  const float ob = out_b[0];
  const float bq0 = bias[0*HID+u], bq1 = bias[1*HID+u],
              bq2 = bias[2*HID+u], bq3 = bias[3*HID+u];
  float c_reg[8];
  #pragma unroll
  for (int j = 0; j < 8; ++j) c_reg[j] = 0.0f;
  __syncthreads();

  for (int st = 0; st < NSTEP; ++st) {
    // ---- encoder: xs load -> relu(xs@W1^T+b1)@W2^T+b2 -> s_xh rows 1..48 ----
    #pragma unroll
    for (int i = 0; i < 3; ++i) {
      int idx = tid + (i << 8);       // 768 = 16*48
      int rr = idx / SDIM, cc = idx - rr*SDIM;
      size_t b = (size_t)blk*ROWS + rr;
      s_xs[rr*49 + cc] = x_statics[(b*TFULL + st)*SDIM + cc];
    }
    __syncthreads();
    #pragma unroll
    for (int i = 0; i < 3; ++i) {
      int idx = tid + (i << 8);
      int rr = idx / SDIM, jj = idx - rr*SDIM;
      float s = s_b1[jj];
      #pragma unroll 8
      for (int k = 0; k < SDIM; ++k)
        s += s_xs[rr*49 + k] * __bfloat162float(s_w1[jj*49 + k]);
      s_e1[rr*49 + jj] = fmaxf(s, 0.0f);
    }
    __syncthreads();
    #pragma unroll
    for (int i = 0; i < 3; ++i) {
      int idx = tid + (i << 8);
      int rr = idx / SDIM, jj = idx - rr*SDIM;
      float s = s_b2[jj];
      #pragma unroll 8
      for (int k = 0; k < SDIM; ++k)
        s += s_e1[rr*49 + k] * __bfloat162float(s_w2[jj*49 + k]);
      s_xh[(1 + jj)*17 + rr] = s;
    }
    __syncthreads();

    // ---- gates: acc[j][q] = bias + sum_k xh[k][r0+j] * W[q*128+u][k] ----
    float a0[8], a1[8], a2[8], a3[8];
    #pragma unroll
    for (int j = 0; j < 8; ++j) { a0[j]=bq0; a1[j]=bq1; a2[j]=bq2; a3[j]=bq3; }
    #pragma unroll 2
    for (int k = 0; k < 49; ++k) {                 // x_in part, W_ih f32 from L2
      const float* wr = wih_t + k*NGATE + u;
      float w0 = wr[0], w1v = wr[128], w2v = wr[256], w3v = wr[384];
      const float* xr = s_xh + k*17 + r0;
      #pragma unroll
      for (int j = 0; j < 8; ++j) {
        float xv = xr[j];
        a0[j] += xv*w0; a1[j] += xv*w1v; a2[j] += xv*w2v; a3[j] += xv*w3v;
      }
    }
    #pragma unroll 4
    for (int kk = 0; kk < HID; ++kk) {             // h part, W_hh bf16 from LDS
      const __hip_bfloat16* wr = s_whh + kk*NGATE + u;
      float w0  = __bfloat162float(wr[0]);
      float w1v = __bfloat162float(wr[128]);
      float w2v = __bfloat162float(wr[256]);
      float w3v = __bfloat162float(wr[384]);
      const float* xr = s_xh + (49 + kk)*17 + r0;
      #pragma unroll
      for (int j = 0; j < 8; ++j) {
        float xv = xr[j];
        a0[j] += xv*w0; a1[j] += xv*w1v; a2[j] += xv*w2v; a3[j] += xv*w3v;
      }
    }
    __syncthreads();   // all k-loop reads of old h done before h is overwritten

    // ---- pointwise LSTM cell + pred partials ----
    float psum[8];
    #pragma unroll
    for (int j = 0; j < 8; ++j) {
      float iv = sigm(a0[j]);
      float fv = sigm(a1[j]);
      float gv = tanh_f(a2[j]);
      float ov = sigm(a3[j]);
      float c = fv*c_reg[j] + iv*gv;
      c_reg[j] = c;
      float h = ov * tanh_f(c);
      s_xh[(49 + u)*17 + r0 + j] = h;
      psum[j] = h * ow;
    }
    #pragma unroll
    for (int off = 1; off < 64; off <<= 1) {
      #pragma unroll
      for (int j = 0; j < 8; ++j) psum[j] += __shfl_xor(psum[j], off);
    }
    if ((tid & 63) == 0) {
      int w = tid >> 6;
      #pragma unroll
      for (int j = 0; j < 8; ++j) s_pp[w][j] = psum[j];
    }
    __syncthreads();
    if (tid < ROWS) {
      int rh = tid >> 3, rj = tid & 7;
      float pred = s_pp[2*rh][rj] + s_pp[2*rh + 1][rj] + ob;
      size_t b = (size_t)blk*ROWS + tid;
      out[b*NSTEP + st] = pred;
      // flow for step st+1: teacher iff (st+1) < twin_idx-1, else this pred
      float nf = (st + 1 < twc) ? y_flow[b*TFULL + st + 1] : pred;
      s_xh[tid] = nf;
    }
    __syncthreads();
  }
}

extern "C" void kernel_launch(void* const* d_in, const int* in_sizes, int n_in,
                              void* d_out, int out_size, void* d_ws, size_t ws_size,
                              hipStream_t stream) {
  const float* y_flow    = (const float*)d_in[0];
  const float* x_statics = (const float*)d_in[1];
  const int*   twin      = (const int*)  d_in[2];
  const float* enc_w1    = (const float*)d_in[3];
  const float* enc_b1    = (const float*)d_in[4];
  const float* enc_w2    = (const float*)d_in[5];
  const float* enc_b2    = (const float*)d_in[6];
  const float* w_ih      = (const float*)d_in[7];
  const float* w_hh      = (const float*)d_in[8];
  const float* b_ih      = (const float*)d_in[9];
  const float* b_hh      = (const float*)d_in[10];
  const float* out_w     = (const float*)d_in[11];
  const float* out_b     = (const float*)d_in[12];
  float* out = (float*)d_out;

  char* ws = (char*)d_ws;
  float*          wih_t = (float*)ws;                              // 100352 B
  __hip_bfloat16* whh_t = (__hip_bfloat16*)(ws + 100352);          // 131072 B
  float*          bias  = (float*)(ws + 100352 + 131072);          // 2048 B

  setup_weights<<<64, 256, 0, stream>>>(w_ih, w_hh, b_ih, b_hh, wih_t, whh_t, bias);
  lstm_persistent<<<256, 256, 0, stream>>>(y_flow, x_statics, twin,
                                           enc_w1, enc_b1, enc_w2, enc_b2,
                                           out_w, out_b, wih_t, whh_t, bias, out);
}

// Round 3
// 1145.331 us; speedup vs baseline: 10.8112x; 10.8112x over previous
//
#include <hip/hip_runtime.h>
#include <hip/hip_bf16.h>

#define HID 128
#define SDIM 48
#define NSTEP 511
#define TFULL 512
#define ROWS 16
#define XHS 200            // u16 stride: 400B, 16B-aligned, 2-way banks (free)
#define O1S 88             // u16 stride: 176B, 16B-aligned, 2-way banks (free)
#define WENC_OFF 98304
#define BIAS_BYTE_OFF 208896

typedef unsigned short u16;
typedef unsigned int   u32;
typedef __attribute__((ext_vector_type(8))) short short8;
typedef __attribute__((ext_vector_type(4))) float f32x4;

__device__ __forceinline__ float sigm(float x)  { return 1.0f/(1.0f+__expf(-x)); }
__device__ __forceinline__ float tanh_f(float x){ return 2.0f/(1.0f+__expf(-2.0f*x)) - 1.0f; }
__device__ __forceinline__ u16 f2bf(float f) {
  __hip_bfloat16 h = __float2bfloat16(f);
  return *reinterpret_cast<u16*>(&h);
}
__device__ __forceinline__ u32 pk2(float a, float b) {
  return (u32)f2bf(a) | ((u32)f2bf(b) << 16);
}
__device__ __forceinline__ short8 pack8(float4 a, float4 b) {
  short8 r;
  r[0]=(short)f2bf(a.x); r[1]=(short)f2bf(a.y); r[2]=(short)f2bf(a.z); r[3]=(short)f2bf(a.w);
  r[4]=(short)f2bf(b.x); r[5]=(short)f2bf(b.y); r[6]=(short)f2bf(b.z); r[7]=(short)f2bf(b.w);
  return r;
}

// xh layout (K dim): [0..47]=enc, [48..175]=h, [176]=flow, [177..191]=0
__global__ void setup_weights(const float* __restrict__ w_ih, const float* __restrict__ w_hh,
                              const float* __restrict__ b_ih, const float* __restrict__ b_hh,
                              const float* __restrict__ enc_w1, const float* __restrict__ enc_w2,
                              u16* __restrict__ frags, float* __restrict__ bias) {
  int stride = gridDim.x * blockDim.x;
  int i0 = blockIdx.x * blockDim.x + threadIdx.x;
  // gate fragments: idx = ((mt*6+kt)*64 + l)*8 + j
  for (int idx = i0; idx < 32*6*64*8; idx += stride) {
    int j  = idx & 7;
    int l  = (idx >> 3) & 63;
    int kt = (idx >> 9) % 6;
    int mt = (idx >> 9) / 6;
    int gr = mt*16 + (l & 15);
    int k  = kt*32 + (l >> 4)*8 + j;
    float v = 0.f;
    if (k < 48)        v = w_ih[gr*49 + 1 + k];          // enc part
    else if (k < 176)  v = w_hh[gr*HID + (k - 48)];      // h part
    else if (k == 176) v = w_ih[gr*49 + 0];              // flow
    frags[idx] = f2bf(v);
  }
  // encoder fragments: idx = (((lyr*3+mt)*2+kt)*64 + l)*8 + j
  for (int idx = i0; idx < 2*3*2*64*8; idx += stride) {
    int j   = idx & 7;
    int l   = (idx >> 3) & 63;
    int kt  = (idx >> 9) & 1;
    int mt  = (idx >> 10) % 3;
    int lyr = (idx >> 10) / 3;
    int row = mt*16 + (l & 15);
    int k   = kt*32 + (l >> 4)*8 + j;
    float v = 0.f;
    if (k < SDIM) v = (lyr ? enc_w2 : enc_w1)[row*SDIM + k];
    frags[WENC_OFF + idx] = f2bf(v);
  }
  for (int idx = i0; idx < 512; idx += stride)
    bias[idx] = b_ih[idx] + b_hh[idx];
}

// 256 blocks x 512 threads (8 waves), persistent over 511 steps; 2 barriers/step.
// Wave w owns gate M-tiles {w, w+8, w+16, w+24}: units 16w..16w+15, i/f/g/o in-lane.
// Wave 7 additionally computes enc(st+1) fully intra-wave (no block barriers).
__global__ __launch_bounds__(512, 2)
void lstm_mfma(const float* __restrict__ y_flow,
               const float* __restrict__ x_statics,
               const int* __restrict__ twin_p,
               const float* __restrict__ enc_b1, const float* __restrict__ enc_b2,
               const float* __restrict__ out_w, const float* __restrict__ out_b,
               const u16* __restrict__ frags, const float* __restrict__ bias,
               float* __restrict__ out) {
  __shared__ __attribute__((aligned(16))) u16  s_xh[2][ROWS][XHS];
  __shared__ __attribute__((aligned(16))) u16  s_o1[ROWS][O1S];   // wave-7 private
  __shared__ __attribute__((aligned(16))) float s_pp[8][16];
  __shared__ __attribute__((aligned(16))) float s_bias[512];
  __shared__ __attribute__((aligned(16))) float s_eb1[SDIM];
  __shared__ __attribute__((aligned(16))) float s_eb2[SDIM];

  const int tid = threadIdx.x;
  const int blk = blockIdx.x;
  const int w  = tid >> 6;
  const int l  = tid & 63;
  const int lr = l & 15;     // batch row (N / D-col)
  const int lg = l >> 4;     // lane group
  const size_t b0 = (size_t)blk * ROWS;

  // ---- static gate fragments into registers ----
  short8 wf[4][6];
  #pragma unroll
  for (int q = 0; q < 4; ++q)
    #pragma unroll
    for (int kt = 0; kt < 6; ++kt)
      wf[q][kt] = *(const short8*)(frags + (((w + 8*q)*6 + kt)*64 + l)*8);

  short8 we1[3][2], we2[3][2];
  if (w == 7) {
    #pragma unroll
    for (int mt = 0; mt < 3; ++mt)
      #pragma unroll
      for (int kt = 0; kt < 2; ++kt) {
        we1[mt][kt] = *(const short8*)(frags + WENC_OFF + (((0*3 + mt)*2 + kt)*64 + l)*8);
        we2[mt][kt] = *(const short8*)(frags + WENC_OFF + (((1*3 + mt)*2 + kt)*64 + l)*8);
      }
  }

  float owv[4];
  #pragma unroll
  for (int r = 0; r < 4; ++r) owv[r] = out_w[w*16 + lg*4 + r];
  const float ob  = out_b[0];
  const int   twc = twin_p[0] - 1;   // teacher iff t < twc

  // ---- LDS init (zero + bias fill), then BARRIER before any targeted writes ----
  for (int i = tid; i < 2*ROWS*XHS; i += 512) ((u16*)s_xh)[i] = 0;
  for (int i = tid; i < ROWS*O1S;  i += 512) ((u16*)s_o1)[i] = 0;
  s_bias[tid] = bias[tid];
  if (tid < SDIM) { s_eb1[tid] = enc_b1[tid]; s_eb2[tid] = enc_b2[tid]; }
  __syncthreads();   // race fix: zero-fill fully done before targeted init below

  const float* xrow = x_statics + (size_t)(b0 + lr)*TFULL*SDIM;

  // wave-7 intra-wave encoder: bx -> L1 -> relu -> o1(LDS) -> waitcnt -> L2 -> s_xh[pp][*][0..47]
  auto enc_step = [&](short8 bx0, short8 bx1, int pp) {
    f32x4 a[3];
    #pragma unroll
    for (int mt = 0; mt < 3; ++mt) a[mt] = *(const f32x4*)&s_eb1[mt*16 + lg*4];
    #pragma unroll
    for (int mt = 0; mt < 3; ++mt) {
      a[mt] = __builtin_amdgcn_mfma_f32_16x16x32_bf16(we1[mt][0], bx0, a[mt], 0, 0, 0);
      a[mt] = __builtin_amdgcn_mfma_f32_16x16x32_bf16(we1[mt][1], bx1, a[mt], 0, 0, 0);
    }
    #pragma unroll
    for (int mt = 0; mt < 3; ++mt) {
      *(u32*)&s_o1[lr][mt*16 + lg*4]     = pk2(fmaxf(a[mt][0],0.f), fmaxf(a[mt][1],0.f));
      *(u32*)&s_o1[lr][mt*16 + lg*4 + 2] = pk2(fmaxf(a[mt][2],0.f), fmaxf(a[mt][3],0.f));
    }
    asm volatile("s_waitcnt lgkmcnt(0)" ::: "memory");
    __builtin_amdgcn_sched_barrier(0);
    short8 bo0 = *(const short8*)&s_o1[lr][lg*8];
    short8 bo1 = *(const short8*)&s_o1[lr][32 + lg*8];   // cols 48..63 stay zero
    f32x4 e[3];
    #pragma unroll
    for (int mt = 0; mt < 3; ++mt) e[mt] = *(const f32x4*)&s_eb2[mt*16 + lg*4];
    #pragma unroll
    for (int mt = 0; mt < 3; ++mt) {
      e[mt] = __builtin_amdgcn_mfma_f32_16x16x32_bf16(we2[mt][0], bo0, e[mt], 0, 0, 0);
      e[mt] = __builtin_amdgcn_mfma_f32_16x16x32_bf16(we2[mt][1], bo1, e[mt], 0, 0, 0);
    }
    #pragma unroll
    for (int mt = 0; mt < 3; ++mt) {
      *(u32*)&s_xh[pp][lr][mt*16 + lg*4]     = pk2(e[mt][0], e[mt][1]);
      *(u32*)&s_xh[pp][lr][mt*16 + lg*4 + 2] = pk2(e[mt][2], e[mt][3]);
    }
  };

  // ---- prologue: enc(0) -> s_xh[0]; prefetch xs(1); flow(0) ----
  float4 zf4 = make_float4(0.f, 0.f, 0.f, 0.f);
  float4 xn0a = zf4, xn0b = zf4, xn1a = zf4, xn1b = zf4;   // xs(st+1) f32, in flight
  if (w == 7) {
    float4 c0a = *(const float4*)(xrow + lg*8);
    float4 c0b = *(const float4*)(xrow + lg*8 + 4);
    float4 c1a = zf4, c1b = zf4;
    if (lg < 2) {
      c1a = *(const float4*)(xrow + 32 + lg*8);
      c1b = *(const float4*)(xrow + 32 + lg*8 + 4);
    }
    enc_step(pack8(c0a, c0b), pack8(c1a, c1b), 0);
    xn0a = *(const float4*)(xrow + SDIM + lg*8);
    xn0b = *(const float4*)(xrow + SDIM + lg*8 + 4);
    if (lg < 2) {
      xn1a = *(const float4*)(xrow + SDIM + 32 + lg*8);
      xn1b = *(const float4*)(xrow + SDIM + 32 + lg*8 + 4);
    }
  }
  if (tid < ROWS && 0 < twc)
    s_xh[0][tid][176] = f2bf(y_flow[(b0 + tid)*TFULL]);
  float c_reg[4] = {0.f, 0.f, 0.f, 0.f};
  __syncthreads();

  // ---- main loop: 2 barriers per step ----
  for (int st = 0; st < NSTEP; ++st) {
    const int p  = st & 1;
    const int p2 = p ^ 1;

    short8 bh[6];
    #pragma unroll
    for (int kt = 0; kt < 6; ++kt)
      bh[kt] = *(const short8*)&s_xh[p][lr][kt*32 + lg*8];

    float tfv = 0.f;
    if (tid < ROWS) tfv = y_flow[(b0 + tid)*TFULL + st + 1];

    short8 bx0 = {}, bx1 = {};
    if (w == 7) {
      bx0 = pack8(xn0a, xn0b);             // xs(st+1), loaded last iter
      bx1 = pack8(xn1a, xn1b);
      const int tt = (st + 2 < TFULL) ? (st + 2) : (TFULL - 1);   // OOB clamp
      xn0a = *(const float4*)(xrow + (size_t)tt*SDIM + lg*8);
      xn0b = *(const float4*)(xrow + (size_t)tt*SDIM + lg*8 + 4);
      if (lg < 2) {
        xn1a = *(const float4*)(xrow + (size_t)tt*SDIM + 32 + lg*8);
        xn1b = *(const float4*)(xrow + (size_t)tt*SDIM + 32 + lg*8 + 4);
      }
    }

    // gate MFMAs: acc[q] over 6 k-tiles, A static in regs, B from LDS
    f32x4 acc[4];
    #pragma unroll
    for (int q = 0; q < 4; ++q) acc[q] = *(const f32x4*)&s_bias[(w + 8*q)*16 + lg*4];
    #pragma unroll
    for (int kt = 0; kt < 6; ++kt)
      #pragma unroll
      for (int q = 0; q < 4; ++q)
        acc[q] = __builtin_amdgcn_mfma_f32_16x16x32_bf16(wf[q][kt], bh[kt], acc[q], 0, 0, 0);

    if (w == 7) enc_step(bx0, bx1, p2);    // enc(st+1) -> s_xh[p2][*][0..47]

    // LSTM cell: lane owns units u = 16w + lg*4 + r, batch row lr
    float hv[4];
    float hsum = 0.f;
    #pragma unroll
    for (int r = 0; r < 4; ++r) {
      float iv = sigm(acc[0][r]);
      float fv = sigm(acc[1][r]);
      float gv = tanh_f(acc[2][r]);
      float ov = sigm(acc[3][r]);
      float c  = fv*c_reg[r] + iv*gv;
      c_reg[r] = c;
      hv[r] = ov*tanh_f(c);
      hsum += hv[r]*owv[r];
    }
    *(u32*)&s_xh[p2][lr][48 + w*16 + lg*4]     = pk2(hv[0], hv[1]);
    *(u32*)&s_xh[p2][lr][48 + w*16 + lg*4 + 2] = pk2(hv[2], hv[3]);
    hsum += __shfl_xor(hsum, 16);
    hsum += __shfl_xor(hsum, 32);
    if (l < 16) s_pp[w][l] = hsum;
    __syncthreads();                       // barrier X: h, enc, s_pp all committed

    if (tid < ROWS) {
      float pred = ob;
      #pragma unroll
      for (int ww = 0; ww < 8; ++ww) pred += s_pp[ww][tid];
      out[(b0 + tid)*NSTEP + st] = pred;
      float fl = (st + 1 < twc) ? tfv : pred;
      s_xh[p2][tid][176] = f2bf(fl);
    }
    __syncthreads();                       // barrier Y: flow visible before next bh reads
  }
}

extern "C" void kernel_launch(void* const* d_in, const int* in_sizes, int n_in,
                              void* d_out, int out_size, void* d_ws, size_t ws_size,
                              hipStream_t stream) {
  const float* y_flow    = (const float*)d_in[0];
  const float* x_statics = (const float*)d_in[1];
  const int*   twin      = (const int*)  d_in[2];
  const float* enc_w1    = (const float*)d_in[3];
  const float* enc_b1    = (const float*)d_in[4];
  const float* enc_w2    = (const float*)d_in[5];
  const float* enc_b2    = (const float*)d_in[6];
  const float* w_ih      = (const float*)d_in[7];
  const float* w_hh      = (const float*)d_in[8];
  const float* b_ih      = (const float*)d_in[9];
  const float* b_hh      = (const float*)d_in[10];
  const float* out_w     = (const float*)d_in[11];
  const float* out_b     = (const float*)d_in[12];
  float* out = (float*)d_out;

  char* ws = (char*)d_ws;
  u16*   frags = (u16*)ws;
  float* bias  = (float*)(ws + BIAS_BYTE_OFF);

  setup_weights<<<128, 256, 0, stream>>>(w_ih, w_hh, b_ih, b_hh, enc_w1, enc_w2, frags, bias);
  lstm_mfma<<<256, 512, 0, stream>>>(y_flow, x_statics, twin,
                                     enc_b1, enc_b2, out_w, out_b,
                                     frags, bias, out);
}